// Round 17
// baseline (184.104 us; speedup 1.0000x reference)
//
#include <hip/hip_runtime.h>

#define IN_DIM 128
#define H1 32
#define H2 16
#define PAD 160   // padded bin capacity: Poisson(64) edges/node, 160 = +12 sigma
#define XNODES 8

// ================= fused: bin-fill w/ count (blocks 0..FB-1) || mm1 (FB..) ===
__global__ void k_fill_mm1(const int* __restrict__ row, const int* __restrict__ col,
                           int* __restrict__ deg, int* __restrict__ csrpad, int E,
                           const float* __restrict__ x, const float* __restrict__ W1,
                           float* __restrict__ hout, int N, int fillBlocks) {
    __shared__ float Ws[IN_DIM * H1];          // 16 KB
    __shared__ float xs[XNODES][IN_DIM];       // 4 KB
    if ((int)blockIdx.x < fillBlocks) {
        int e = blockIdx.x * blockDim.x + threadIdx.x;
        if (e < E) {
            int c = col[e];
            int pos = atomicAdd(&deg[c], 1);
            csrpad[(long)c * PAD + pos] = row[e];
        }
        return;   // whole block exits; no barrier crossed
    }
    int t = threadIdx.x;
    int i0 = ((int)blockIdx.x - fillBlocks) * XNODES;
    const float4* W4 = reinterpret_cast<const float4*>(W1);
    float4* Ws4 = reinterpret_cast<float4*>(Ws);
#pragma unroll
    for (int i = t; i < IN_DIM * H1 / 4; i += 256) Ws4[i] = W4[i];
    const float4* xg = reinterpret_cast<const float4*>(x + (long)i0 * IN_DIM);
    float4* xs4 = reinterpret_cast<float4*>(xs);
    xs4[t] = xg[t];   // XNODES*IN_DIM/4 == 256 exactly
    __syncthreads();
    int n = t >> 5, d = t & 31;
    float acc = 0.f;
#pragma unroll 8
    for (int k = 0; k < IN_DIM; ++k) acc = fmaf(xs[n][k], Ws[k * H1 + d], acc);
    int i = i0 + n;
    if (i < N) hout[(long)i * H1 + d] = acc;
}

// ================= prep: dinv = rsqrt(deg+1); h *= dinv (in place) ===========
__global__ void k_prep(const int* __restrict__ deg, float* __restrict__ dinv,
                       float* __restrict__ h, int N) {
    int i = blockIdx.x * blockDim.x + threadIdx.x;
    if (i >= N) return;
    float di = rsqrtf((float)deg[i] + 1.0f);
    dinv[i] = di;
    float4* hp = reinterpret_cast<float4*>(h + (long)i * H1);
#pragma unroll
    for (int q = 0; q < H1 / 4; ++q) {
        float4 v = hp[q];
        v.x *= di; v.y *= di; v.z *= di; v.w *= di;
        hp[q] = v;
    }
}

// ================= fused gather1 + mm2 (padded bins, 8-deep MLP) =============
__global__ void k_g1mm2(const int* __restrict__ deg, const int* __restrict__ csrpad,
                        const float* __restrict__ dinv, const float* __restrict__ hp,
                        const float* __restrict__ b1, const float* __restrict__ W2,
                        float* __restrict__ h2p, int N) {
    __shared__ float W2s[H1 * H2];     // 2 KB
    __shared__ float h1s[4][H1];       // per-wave slot
    int t = threadIdx.x;
    for (int i = t; i < H1 * H2; i += blockDim.x) W2s[i] = W2[i];
    __syncthreads();
    int wv = t >> 6;
    int lane = t & 63;
    int c = blockIdx.x * 4 + wv;
    bool active = (c < N);
    int cc = active ? c : (N - 1);     // clamp: inactive waves do harmless reads
    constexpr int C4 = H1 / 4;         // 8 float4 chunks
    constexpr int SUB = 64 / C4;       // 8 edges per wave-iter
    int sub = lane / C4, d4 = lane % C4;
    int cnt = deg[cc];
    const int* bin = csrpad + (long)cc * PAD;
    const float4* hp4 = reinterpret_cast<const float4*>(hp);

    float4 A0 = make_float4(0.f, 0.f, 0.f, 0.f), A1 = A0, A2 = A0, A3 = A0;
    int k = sub;
    for (; k + 7 * SUB < cnt; k += 8 * SUB) {   // 8 loads in flight (cnt~64 -> one batch)
        int s0 = bin[k];
        int s1 = bin[k + SUB];
        int s2 = bin[k + 2 * SUB];
        int s3 = bin[k + 3 * SUB];
        int s4 = bin[k + 4 * SUB];
        int s5 = bin[k + 5 * SUB];
        int s6 = bin[k + 6 * SUB];
        int s7 = bin[k + 7 * SUB];
        float4 v0 = hp4[(long)s0 * C4 + d4];
        float4 v1 = hp4[(long)s1 * C4 + d4];
        float4 v2 = hp4[(long)s2 * C4 + d4];
        float4 v3 = hp4[(long)s3 * C4 + d4];
        float4 v4 = hp4[(long)s4 * C4 + d4];
        float4 v5 = hp4[(long)s5 * C4 + d4];
        float4 v6 = hp4[(long)s6 * C4 + d4];
        float4 v7 = hp4[(long)s7 * C4 + d4];
        A0.x += v0.x; A0.y += v0.y; A0.z += v0.z; A0.w += v0.w;
        A1.x += v1.x; A1.y += v1.y; A1.z += v1.z; A1.w += v1.w;
        A2.x += v2.x; A2.y += v2.y; A2.z += v2.z; A2.w += v2.w;
        A3.x += v3.x; A3.y += v3.y; A3.z += v3.z; A3.w += v3.w;
        A0.x += v4.x; A0.y += v4.y; A0.z += v4.z; A0.w += v4.w;
        A1.x += v5.x; A1.y += v5.y; A1.z += v5.z; A1.w += v5.w;
        A2.x += v6.x; A2.y += v6.y; A2.z += v6.z; A2.w += v6.w;
        A3.x += v7.x; A3.y += v7.y; A3.z += v7.z; A3.w += v7.w;
    }
    for (; k + 3 * SUB < cnt; k += 4 * SUB) {
        int s0 = bin[k];
        int s1 = bin[k + SUB];
        int s2 = bin[k + 2 * SUB];
        int s3 = bin[k + 3 * SUB];
        float4 v0 = hp4[(long)s0 * C4 + d4];
        float4 v1 = hp4[(long)s1 * C4 + d4];
        float4 v2 = hp4[(long)s2 * C4 + d4];
        float4 v3 = hp4[(long)s3 * C4 + d4];
        A0.x += v0.x; A0.y += v0.y; A0.z += v0.z; A0.w += v0.w;
        A1.x += v1.x; A1.y += v1.y; A1.z += v1.z; A1.w += v1.w;
        A2.x += v2.x; A2.y += v2.y; A2.z += v2.z; A2.w += v2.w;
        A3.x += v3.x; A3.y += v3.y; A3.z += v3.z; A3.w += v3.w;
    }
    for (; k < cnt; k += SUB) {
        float4 v = hp4[(long)bin[k] * C4 + d4];
        A0.x += v.x; A0.y += v.y; A0.z += v.z; A0.w += v.w;
    }
    float4 acc;
    acc.x = (A0.x + A1.x) + (A2.x + A3.x);
    acc.y = (A0.y + A1.y) + (A2.y + A3.y);
    acc.z = (A0.z + A1.z) + (A2.z + A3.z);
    acc.w = (A0.w + A1.w) + (A2.w + A3.w);
#pragma unroll
    for (int off = C4; off < 64; off <<= 1) {
        acc.x += __shfl_xor(acc.x, off, 64);
        acc.y += __shfl_xor(acc.y, off, 64);
        acc.z += __shfl_xor(acc.z, off, 64);
        acc.w += __shfl_xor(acc.w, off, 64);
    }
    if (lane < C4) {
        float di = dinv[cc];
        float4 self = hp4[(long)cc * C4 + d4];
        float4 bv = reinterpret_cast<const float4*>(b1)[d4];
        float4 v;
        v.x = fmaxf(fmaf(di, acc.x + self.x, bv.x), 0.f);
        v.y = fmaxf(fmaf(di, acc.y + self.y, bv.y), 0.f);
        v.z = fmaxf(fmaf(di, acc.z + self.z, bv.z), 0.f);
        v.w = fmaxf(fmaf(di, acc.w + self.w, bv.w), 0.f);
        reinterpret_cast<float4*>(h1s[wv])[d4] = v;
    }
    __syncthreads();   // all threads reach (no early returns)
    if (active && lane < H2) {
        float z = 0.f;
#pragma unroll
        for (int kk = 0; kk < H1; ++kk) z = fmaf(h1s[wv][kk], W2s[kk * H2 + lane], z);
        h2p[(long)c * H2 + lane] = z * dinv[c];
    }
}

// ================= gather layer 2 (padded bins), float4 lanes ================
template <int D, bool RELU>
__global__ void k_gather(const int* __restrict__ deg, const int* __restrict__ csrpad,
                         const float* __restrict__ dinv, const float* __restrict__ hp,
                         const float* __restrict__ bias, float* __restrict__ out, int N) {
    constexpr int C4  = D / 4;
    constexpr int SUB = 64 / C4;
    int c = blockIdx.x * (blockDim.x >> 6) + (threadIdx.x >> 6);
    if (c >= N) return;
    int lane = threadIdx.x & 63;
    int sub = lane / C4, d4 = lane % C4;
    int cnt = deg[c];
    const int* bin = csrpad + (long)c * PAD;
    const float4* hp4 = reinterpret_cast<const float4*>(hp);

    float4 A0 = make_float4(0.f, 0.f, 0.f, 0.f), A1 = A0, A2 = A0, A3 = A0;
    int k = sub;
    for (; k + 3 * SUB < cnt; k += 4 * SUB) {
        int s0 = bin[k];
        int s1 = bin[k + SUB];
        int s2 = bin[k + 2 * SUB];
        int s3 = bin[k + 3 * SUB];
        float4 v0 = hp4[(long)s0 * C4 + d4];
        float4 v1 = hp4[(long)s1 * C4 + d4];
        float4 v2 = hp4[(long)s2 * C4 + d4];
        float4 v3 = hp4[(long)s3 * C4 + d4];
        A0.x += v0.x; A0.y += v0.y; A0.z += v0.z; A0.w += v0.w;
        A1.x += v1.x; A1.y += v1.y; A1.z += v1.z; A1.w += v1.w;
        A2.x += v2.x; A2.y += v2.y; A2.z += v2.z; A2.w += v2.w;
        A3.x += v3.x; A3.y += v3.y; A3.z += v3.z; A3.w += v3.w;
    }
    for (; k < cnt; k += SUB) {
        float4 v = hp4[(long)bin[k] * C4 + d4];
        A0.x += v.x; A0.y += v.y; A0.z += v.z; A0.w += v.w;
    }
    float4 acc;
    acc.x = (A0.x + A1.x) + (A2.x + A3.x);
    acc.y = (A0.y + A1.y) + (A2.y + A3.y);
    acc.z = (A0.z + A1.z) + (A2.z + A3.z);
    acc.w = (A0.w + A1.w) + (A2.w + A3.w);
#pragma unroll
    for (int off = C4; off < 64; off <<= 1) {
        acc.x += __shfl_xor(acc.x, off, 64);
        acc.y += __shfl_xor(acc.y, off, 64);
        acc.z += __shfl_xor(acc.z, off, 64);
        acc.w += __shfl_xor(acc.w, off, 64);
    }
    if (lane < C4) {
        float di = dinv[c];
        float4 self = hp4[(long)c * C4 + d4];
        float4 bv = reinterpret_cast<const float4*>(bias)[d4];
        float4 v;
        v.x = fmaf(di, acc.x + self.x, bv.x);
        v.y = fmaf(di, acc.y + self.y, bv.y);
        v.z = fmaf(di, acc.z + self.z, bv.z);
        v.w = fmaf(di, acc.w + self.w, bv.w);
        if (RELU) {
            v.x = fmaxf(v.x, 0.f); v.y = fmaxf(v.y, 0.f);
            v.z = fmaxf(v.z, 0.f); v.w = fmaxf(v.w, 0.f);
        }
        reinterpret_cast<float4*>(out + (long)c * D)[d4] = v;
    }
}

// ================= atomic fallback path =================

__global__ void k_count(const int* __restrict__ col, int* __restrict__ deg, int E) {
    int e = blockIdx.x * blockDim.x + threadIdx.x;
    if (e < E) atomicAdd(&deg[col[e]], 1);
}

template <int KD, int OD, bool SCALE>
__global__ void k_mm(const float* __restrict__ xin, const float* __restrict__ W,
                     const float* __restrict__ dinv, float* __restrict__ hout, int N) {
    __shared__ float Ws[KD * OD];
    for (int t = threadIdx.x; t < KD * OD; t += blockDim.x) Ws[t] = W[t];
    __syncthreads();
    int idx = blockIdx.x * blockDim.x + threadIdx.x;
    int i = idx / OD, d = idx % OD;
    if (i >= N) return;
    const float4* xr = reinterpret_cast<const float4*>(xin + (long)i * KD);
    float acc = 0.f;
#pragma unroll
    for (int k4 = 0; k4 < KD / 4; ++k4) {
        float4 xv = xr[k4];
        acc = fmaf(xv.x, Ws[(4 * k4 + 0) * OD + d], acc);
        acc = fmaf(xv.y, Ws[(4 * k4 + 1) * OD + d], acc);
        acc = fmaf(xv.z, Ws[(4 * k4 + 2) * OD + d], acc);
        acc = fmaf(xv.w, Ws[(4 * k4 + 3) * OD + d], acc);
    }
    hout[idx] = SCALE ? acc * dinv[i] : acc;
}

__global__ void k_dinv_i(const int* __restrict__ deg, float* __restrict__ dinv, int N) {
    int i = blockIdx.x * blockDim.x + threadIdx.x;
    if (i < N) dinv[i] = rsqrtf((float)deg[i] + 1.0f);
}

template <int D>
__global__ void k_scatter(const int* __restrict__ row, const int* __restrict__ col,
                          const float* __restrict__ dinv, const float* __restrict__ hin,
                          float* __restrict__ agg, int E) {
    int idx = blockIdx.x * blockDim.x + threadIdx.x;
    int e = idx / D, d = idx % D;
    if (e >= E) return;
    int r = row[e], c = col[e];
    float nrm = dinv[r] * dinv[c];
    atomicAdd(&agg[(long)c * D + d], hin[(long)r * D + d] * nrm);
}

template <int D, bool RELU>
__global__ void k_finish(const float* __restrict__ hproj, const float* __restrict__ dinv,
                         const float* __restrict__ bias, float* __restrict__ agg, int N) {
    int idx = blockIdx.x * blockDim.x + threadIdx.x;
    if (idx >= N * D) return;
    int i = idx / D, d = idx % D;
    float di = dinv[i];
    float v = agg[idx] + hproj[idx] * di * di + bias[d];
    agg[idx] = RELU ? fmaxf(v, 0.f) : v;
}

// ================= decode: out[i][j] = dot(z[i], z[j]) — symmetric ==========
// R17: out is symmetric. 128x128 tiles, triangular grid (tj>=ti): stage zi/zj
// ONCE, then two sequential compute+store passes — acc for (ti,tj), LDS-reused
// acc for (tj,ti). Halves blocks (6241->3160), staging reads, and barriers;
// write bytes and per-output k-order unchanged -> bit-identical results.
// 512 threads, acc[8][4] per pass, ty=t>>5 (rows ty*8..+7), tx=t&31 (cols tx*4).
#define DS 128

__global__ __launch_bounds__(512, 8)
void k_decode(const float* __restrict__ z, float* __restrict__ out, int N) {
    __shared__ float ziT[16][DS];   // 8 KB
    __shared__ float zjT[16][DS];   // 8 KB
    int ti = blockIdx.y, tj = blockIdx.x;
    if (tj < ti) return;            // triangular: mirror handled by pass 2
    int bi = ti * DS, bj = tj * DS;
    int t = threadIdx.x;

    {
        // 512 threads load 256 rows x 64B: thread t -> row (t>>1), 32B half (t&1)
        int r = (t >> 1) & 127;
        int gi = (t < 256 ? bi : bj) + r;
        int half = t & 1;
        float4 v0 = make_float4(0.f, 0.f, 0.f, 0.f), v1 = v0;
        if (gi < N) {
            const float4* zp = reinterpret_cast<const float4*>(z + (long)gi * 16);
            v0 = zp[half * 2];
            v1 = zp[half * 2 + 1];
        }
        float vals[8] = {v0.x, v0.y, v0.z, v0.w, v1.x, v1.y, v1.z, v1.w};
        float (*dst)[DS] = (t < 256) ? ziT : zjT;
        int k0 = half * 8;
#pragma unroll
        for (int k = 0; k < 8; ++k) dst[k0 + k][r] = vals[k];
    }
    __syncthreads();

    int tx = t & 31, ty = t >> 5;   // ty 0..15: rows ty*8..+7; tx 0..31: cols tx*4..+3

    // ---- pass 1: out[bi..][bj..] from (ziT rows) x (zjT cols) ----
    {
        float acc[8][4] = {};
#pragma unroll 4
        for (int k = 0; k < 16; ++k) {
            float a[8], b[4];
            float4 a0 = *reinterpret_cast<const float4*>(&ziT[k][ty * 8]);
            float4 a1 = *reinterpret_cast<const float4*>(&ziT[k][ty * 8 + 4]);
            float4 b0 = *reinterpret_cast<const float4*>(&zjT[k][tx * 4]);
            a[0]=a0.x; a[1]=a0.y; a[2]=a0.z; a[3]=a0.w; a[4]=a1.x; a[5]=a1.y; a[6]=a1.z; a[7]=a1.w;
            b[0]=b0.x; b[1]=b0.y; b[2]=b0.z; b[3]=b0.w;
#pragma unroll
            for (int u = 0; u < 8; ++u)
#pragma unroll
                for (int v = 0; v < 4; ++v)
                    acc[u][v] = fmaf(a[u], b[v], acc[u][v]);
        }
#pragma unroll
        for (int u = 0; u < 8; ++u) {
            int gi = bi + ty * 8 + u;
            if (gi >= N) continue;
            int gj = bj + tx * 4;
            long base = (long)gi * N + gj;
            if (gj + 3 < N) {
                *reinterpret_cast<float4*>(&out[base]) =
                    make_float4(acc[u][0], acc[u][1], acc[u][2], acc[u][3]);
            } else {
                for (int v2 = 0; v2 < 4; ++v2)
                    if (gj + v2 < N) out[base + v2] = acc[u][v2];
            }
        }
    }

    // ---- pass 2 (off-diagonal only): out[bj..][bi..] from (zjT rows) x (ziT cols)
    if (ti != tj) {
        float acc[8][4] = {};
#pragma unroll 4
        for (int k = 0; k < 16; ++k) {
            float a[8], b[4];
            float4 a0 = *reinterpret_cast<const float4*>(&zjT[k][ty * 8]);
            float4 a1 = *reinterpret_cast<const float4*>(&zjT[k][ty * 8 + 4]);
            float4 b0 = *reinterpret_cast<const float4*>(&ziT[k][tx * 4]);
            a[0]=a0.x; a[1]=a0.y; a[2]=a0.z; a[3]=a0.w; a[4]=a1.x; a[5]=a1.y; a[6]=a1.z; a[7]=a1.w;
            b[0]=b0.x; b[1]=b0.y; b[2]=b0.z; b[3]=b0.w;
#pragma unroll
            for (int u = 0; u < 8; ++u)
#pragma unroll
                for (int v = 0; v < 4; ++v)
                    acc[u][v] = fmaf(a[u], b[v], acc[u][v]);
        }
#pragma unroll
        for (int u = 0; u < 8; ++u) {
            int gi = bj + ty * 8 + u;
            if (gi >= N) continue;
            int gj = bi + tx * 4;
            long base = (long)gi * N + gj;
            if (gj + 3 < N) {
                *reinterpret_cast<float4*>(&out[base]) =
                    make_float4(acc[u][0], acc[u][1], acc[u][2], acc[u][3]);
            } else {
                for (int v2 = 0; v2 < 4; ++v2)
                    if (gj + v2 < N) out[base + v2] = acc[u][v2];
            }
        }
    }
}

// ================= launch =================

extern "C" void kernel_launch(void* const* d_in, const int* in_sizes, int n_in,
                              void* d_out, int out_size, void* d_ws, size_t ws_size,
                              hipStream_t stream) {
    const float* x  = (const float*)d_in[0];
    const int*   ei = (const int*)d_in[1];
    const float* W1 = (const float*)d_in[2];
    const float* b1 = (const float*)d_in[3];
    const float* W2 = (const float*)d_in[4];
    const float* b2 = (const float*)d_in[5];
    float* out = (float*)d_out;

    const int N = in_sizes[0] / IN_DIM;   // 10000
    const int E = in_sizes[1] / 2;        // 640000
    const int* row = ei;
    const int* col = ei + E;

    const long SZ_DEG = (N + 15) & ~15L;        // 10000
    const long SZ_BIN = (long)N * PAD;          // 1.6M ints (PAD=160)
    const long SZ_DI  = SZ_DEG;
    const long need = SZ_DEG + SZ_BIN + SZ_DI
                    + (long)N * H1 + 2L * N * H2;

    const int T = (N + DS - 1) / DS;            // 79
    dim3 dgrid(T, T);

    if (ws_size >= (size_t)need * 4) {
        // ---- padded-bin path (6 dispatches incl. decode) ----
        int*   deg    = (int*)d_ws;
        int*   csrpad = deg + SZ_DEG;
        float* dinv   = (float*)(csrpad + SZ_BIN);
        float* h      = dinv + SZ_DI;        // x@W1 (raw, then *dinv in k_prep)
        float* h2p    = h + (long)N * H1;    // (h1@W2)*dinv  (N*H2)
        float* zz     = h2p + (long)N * H2;  // z             (N*H2), 64B-aligned

        hipMemsetAsync(deg, 0, (size_t)N * sizeof(int), stream);

        int fillBlocks = (E + 255) / 256;                    // 2500
        int mmBlocks   = (N + XNODES - 1) / XNODES;          // 1250
        k_fill_mm1<<<fillBlocks + mmBlocks, 256, 0, stream>>>(
            row, col, deg, csrpad, E, x, W1, h, N, fillBlocks);

        k_prep<<<(N + 255) / 256, 256, 0, stream>>>(deg, dinv, h, N);

        k_g1mm2<<<(N + 3) / 4, 256, 0, stream>>>(deg, csrpad, dinv, h, b1, W2, h2p, N);
        k_gather<H2, false><<<(N + 3) / 4, 256, 0, stream>>>(deg, csrpad, dinv, h2p, b2, zz, N);

        k_decode<<<dgrid, 512, 0, stream>>>(zz, out, N);
    } else {
        // ---- fallback: atomic scatter path ----
        int*   deg  = (int*)d_ws;
        float* dinv = (float*)(deg + SZ_DEG);
        float* h    = dinv + SZ_DI;
        float* h1   = h + (long)N * H1;
        float* h2   = h1 + (long)N * H1;
        float* zz   = h2 + (long)N * H2;

        hipMemsetAsync(deg, 0, (size_t)N * sizeof(int), stream);
        hipMemsetAsync(h1, 0, (size_t)N * H1 * sizeof(float), stream);
        hipMemsetAsync(zz, 0, (size_t)N * H2 * sizeof(float), stream);

        k_count<<<(E + 255) / 256, 256, 0, stream>>>(col, deg, E);
        k_dinv_i<<<(N + 255) / 256, 256, 0, stream>>>(deg, dinv, N);

        k_mm<IN_DIM, H1, false><<<((long)N * H1 + 255) / 256, 256, 0, stream>>>(x, W1, dinv, h, N);
        k_scatter<H1><<<((long)E * H1 + 255) / 256, 256, 0, stream>>>(row, col, dinv, h, h1, E);
        k_finish<H1, true><<<((long)N * H1 + 255) / 256, 256, 0, stream>>>(h, dinv, b1, h1, N);

        k_mm<H1, H2, false><<<((long)N * H2 + 255) / 256, 256, 0, stream>>>(h1, W2, dinv, h2, N);
        k_scatter<H2><<<((long)E * H2 + 255) / 256, 256, 0, stream>>>(row, col, dinv, h2, zz, E);
        k_finish<H2, false><<<((long)N * H2 + 255) / 256, 256, 0, stream>>>(h2, dinv, b2, zz, N);

        k_decode<<<dgrid, 512, 0, stream>>>(zz, out, N);
    }
}

// Round 18
// 167.210 us; speedup vs baseline: 1.1010x; 1.1010x over previous
//
#include <hip/hip_runtime.h>

#define IN_DIM 128
#define H1 32
#define H2 16
#define PAD 160   // padded bin capacity: Poisson(64) edges/node, 160 = +12 sigma
#define XNODES 8

// ================= fused: bin-fill w/ count (blocks 0..FB-1) || mm1 (FB..) ===
__global__ void k_fill_mm1(const int* __restrict__ row, const int* __restrict__ col,
                           int* __restrict__ deg, int* __restrict__ csrpad, int E,
                           const float* __restrict__ x, const float* __restrict__ W1,
                           float* __restrict__ hout, int N, int fillBlocks) {
    __shared__ float Ws[IN_DIM * H1];          // 16 KB
    __shared__ float xs[XNODES][IN_DIM];       // 4 KB
    if ((int)blockIdx.x < fillBlocks) {
        int e = blockIdx.x * blockDim.x + threadIdx.x;
        if (e < E) {
            int c = col[e];
            int pos = atomicAdd(&deg[c], 1);
            csrpad[(long)c * PAD + pos] = row[e];
        }
        return;   // whole block exits; no barrier crossed
    }
    int t = threadIdx.x;
    int i0 = ((int)blockIdx.x - fillBlocks) * XNODES;
    const float4* W4 = reinterpret_cast<const float4*>(W1);
    float4* Ws4 = reinterpret_cast<float4*>(Ws);
#pragma unroll
    for (int i = t; i < IN_DIM * H1 / 4; i += 256) Ws4[i] = W4[i];
    const float4* xg = reinterpret_cast<const float4*>(x + (long)i0 * IN_DIM);
    float4* xs4 = reinterpret_cast<float4*>(xs);
    xs4[t] = xg[t];   // XNODES*IN_DIM/4 == 256 exactly
    __syncthreads();
    int n = t >> 5, d = t & 31;
    float acc = 0.f;
#pragma unroll 8
    for (int k = 0; k < IN_DIM; ++k) acc = fmaf(xs[n][k], Ws[k * H1 + d], acc);
    int i = i0 + n;
    if (i < N) hout[(long)i * H1 + d] = acc;
}

// ================= prep: dinv = rsqrt(deg+1); h *= dinv (in place) ===========
__global__ void k_prep(const int* __restrict__ deg, float* __restrict__ dinv,
                       float* __restrict__ h, int N) {
    int i = blockIdx.x * blockDim.x + threadIdx.x;
    if (i >= N) return;
    float di = rsqrtf((float)deg[i] + 1.0f);
    dinv[i] = di;
    float4* hp = reinterpret_cast<float4*>(h + (long)i * H1);
#pragma unroll
    for (int q = 0; q < H1 / 4; ++q) {
        float4 v = hp[q];
        v.x *= di; v.y *= di; v.z *= di; v.w *= di;
        hp[q] = v;
    }
}

// ================= fused gather1 + mm2 (padded bins, 8-deep MLP) =============
__global__ void k_g1mm2(const int* __restrict__ deg, const int* __restrict__ csrpad,
                        const float* __restrict__ dinv, const float* __restrict__ hp,
                        const float* __restrict__ b1, const float* __restrict__ W2,
                        float* __restrict__ h2p, int N) {
    __shared__ float W2s[H1 * H2];     // 2 KB
    __shared__ float h1s[4][H1];       // per-wave slot
    int t = threadIdx.x;
    for (int i = t; i < H1 * H2; i += blockDim.x) W2s[i] = W2[i];
    __syncthreads();
    int wv = t >> 6;
    int lane = t & 63;
    int c = blockIdx.x * 4 + wv;
    bool active = (c < N);
    int cc = active ? c : (N - 1);     // clamp: inactive waves do harmless reads
    constexpr int C4 = H1 / 4;         // 8 float4 chunks
    constexpr int SUB = 64 / C4;       // 8 edges per wave-iter
    int sub = lane / C4, d4 = lane % C4;
    int cnt = deg[cc];
    const int* bin = csrpad + (long)cc * PAD;
    const float4* hp4 = reinterpret_cast<const float4*>(hp);

    float4 A0 = make_float4(0.f, 0.f, 0.f, 0.f), A1 = A0, A2 = A0, A3 = A0;
    int k = sub;
    for (; k + 7 * SUB < cnt; k += 8 * SUB) {   // 8 loads in flight (cnt~64 -> one batch)
        int s0 = bin[k];
        int s1 = bin[k + SUB];
        int s2 = bin[k + 2 * SUB];
        int s3 = bin[k + 3 * SUB];
        int s4 = bin[k + 4 * SUB];
        int s5 = bin[k + 5 * SUB];
        int s6 = bin[k + 6 * SUB];
        int s7 = bin[k + 7 * SUB];
        float4 v0 = hp4[(long)s0 * C4 + d4];
        float4 v1 = hp4[(long)s1 * C4 + d4];
        float4 v2 = hp4[(long)s2 * C4 + d4];
        float4 v3 = hp4[(long)s3 * C4 + d4];
        float4 v4 = hp4[(long)s4 * C4 + d4];
        float4 v5 = hp4[(long)s5 * C4 + d4];
        float4 v6 = hp4[(long)s6 * C4 + d4];
        float4 v7 = hp4[(long)s7 * C4 + d4];
        A0.x += v0.x; A0.y += v0.y; A0.z += v0.z; A0.w += v0.w;
        A1.x += v1.x; A1.y += v1.y; A1.z += v1.z; A1.w += v1.w;
        A2.x += v2.x; A2.y += v2.y; A2.z += v2.z; A2.w += v2.w;
        A3.x += v3.x; A3.y += v3.y; A3.z += v3.z; A3.w += v3.w;
        A0.x += v4.x; A0.y += v4.y; A0.z += v4.z; A0.w += v4.w;
        A1.x += v5.x; A1.y += v5.y; A1.z += v5.z; A1.w += v5.w;
        A2.x += v6.x; A2.y += v6.y; A2.z += v6.z; A2.w += v6.w;
        A3.x += v7.x; A3.y += v7.y; A3.z += v7.z; A3.w += v7.w;
    }
    for (; k + 3 * SUB < cnt; k += 4 * SUB) {
        int s0 = bin[k];
        int s1 = bin[k + SUB];
        int s2 = bin[k + 2 * SUB];
        int s3 = bin[k + 3 * SUB];
        float4 v0 = hp4[(long)s0 * C4 + d4];
        float4 v1 = hp4[(long)s1 * C4 + d4];
        float4 v2 = hp4[(long)s2 * C4 + d4];
        float4 v3 = hp4[(long)s3 * C4 + d4];
        A0.x += v0.x; A0.y += v0.y; A0.z += v0.z; A0.w += v0.w;
        A1.x += v1.x; A1.y += v1.y; A1.z += v1.z; A1.w += v1.w;
        A2.x += v2.x; A2.y += v2.y; A2.z += v2.z; A2.w += v2.w;
        A3.x += v3.x; A3.y += v3.y; A3.z += v3.z; A3.w += v3.w;
    }
    for (; k < cnt; k += SUB) {
        float4 v = hp4[(long)bin[k] * C4 + d4];
        A0.x += v.x; A0.y += v.y; A0.z += v.z; A0.w += v.w;
    }
    float4 acc;
    acc.x = (A0.x + A1.x) + (A2.x + A3.x);
    acc.y = (A0.y + A1.y) + (A2.y + A3.y);
    acc.z = (A0.z + A1.z) + (A2.z + A3.z);
    acc.w = (A0.w + A1.w) + (A2.w + A3.w);
#pragma unroll
    for (int off = C4; off < 64; off <<= 1) {
        acc.x += __shfl_xor(acc.x, off, 64);
        acc.y += __shfl_xor(acc.y, off, 64);
        acc.z += __shfl_xor(acc.z, off, 64);
        acc.w += __shfl_xor(acc.w, off, 64);
    }
    if (lane < C4) {
        float di = dinv[cc];
        float4 self = hp4[(long)cc * C4 + d4];
        float4 bv = reinterpret_cast<const float4*>(b1)[d4];
        float4 v;
        v.x = fmaxf(fmaf(di, acc.x + self.x, bv.x), 0.f);
        v.y = fmaxf(fmaf(di, acc.y + self.y, bv.y), 0.f);
        v.z = fmaxf(fmaf(di, acc.z + self.z, bv.z), 0.f);
        v.w = fmaxf(fmaf(di, acc.w + self.w, bv.w), 0.f);
        reinterpret_cast<float4*>(h1s[wv])[d4] = v;
    }
    __syncthreads();   // all threads reach (no early returns)
    if (active && lane < H2) {
        float z = 0.f;
#pragma unroll
        for (int kk = 0; kk < H1; ++kk) z = fmaf(h1s[wv][kk], W2s[kk * H2 + lane], z);
        h2p[(long)c * H2 + lane] = z * dinv[c];
    }
}

// ================= gather layer 2 (padded bins), float4 lanes ================
template <int D, bool RELU>
__global__ void k_gather(const int* __restrict__ deg, const int* __restrict__ csrpad,
                         const float* __restrict__ dinv, const float* __restrict__ hp,
                         const float* __restrict__ bias, float* __restrict__ out, int N) {
    constexpr int C4  = D / 4;
    constexpr int SUB = 64 / C4;
    int c = blockIdx.x * (blockDim.x >> 6) + (threadIdx.x >> 6);
    if (c >= N) return;
    int lane = threadIdx.x & 63;
    int sub = lane / C4, d4 = lane % C4;
    int cnt = deg[c];
    const int* bin = csrpad + (long)c * PAD;
    const float4* hp4 = reinterpret_cast<const float4*>(hp);

    float4 A0 = make_float4(0.f, 0.f, 0.f, 0.f), A1 = A0, A2 = A0, A3 = A0;
    int k = sub;
    for (; k + 3 * SUB < cnt; k += 4 * SUB) {
        int s0 = bin[k];
        int s1 = bin[k + SUB];
        int s2 = bin[k + 2 * SUB];
        int s3 = bin[k + 3 * SUB];
        float4 v0 = hp4[(long)s0 * C4 + d4];
        float4 v1 = hp4[(long)s1 * C4 + d4];
        float4 v2 = hp4[(long)s2 * C4 + d4];
        float4 v3 = hp4[(long)s3 * C4 + d4];
        A0.x += v0.x; A0.y += v0.y; A0.z += v0.z; A0.w += v0.w;
        A1.x += v1.x; A1.y += v1.y; A1.z += v1.z; A1.w += v1.w;
        A2.x += v2.x; A2.y += v2.y; A2.z += v2.z; A2.w += v2.w;
        A3.x += v3.x; A3.y += v3.y; A3.z += v3.z; A3.w += v3.w;
    }
    for (; k < cnt; k += SUB) {
        float4 v = hp4[(long)bin[k] * C4 + d4];
        A0.x += v.x; A0.y += v.y; A0.z += v.z; A0.w += v.w;
    }
    float4 acc;
    acc.x = (A0.x + A1.x) + (A2.x + A3.x);
    acc.y = (A0.y + A1.y) + (A2.y + A3.y);
    acc.z = (A0.z + A1.z) + (A2.z + A3.z);
    acc.w = (A0.w + A1.w) + (A2.w + A3.w);
#pragma unroll
    for (int off = C4; off < 64; off <<= 1) {
        acc.x += __shfl_xor(acc.x, off, 64);
        acc.y += __shfl_xor(acc.y, off, 64);
        acc.z += __shfl_xor(acc.z, off, 64);
        acc.w += __shfl_xor(acc.w, off, 64);
    }
    if (lane < C4) {
        float di = dinv[c];
        float4 self = hp4[(long)c * C4 + d4];
        float4 bv = reinterpret_cast<const float4*>(bias)[d4];
        float4 v;
        v.x = fmaf(di, acc.x + self.x, bv.x);
        v.y = fmaf(di, acc.y + self.y, bv.y);
        v.z = fmaf(di, acc.z + self.z, bv.z);
        v.w = fmaf(di, acc.w + self.w, bv.w);
        if (RELU) {
            v.x = fmaxf(v.x, 0.f); v.y = fmaxf(v.y, 0.f);
            v.z = fmaxf(v.z, 0.f); v.w = fmaxf(v.w, 0.f);
        }
        reinterpret_cast<float4*>(out + (long)c * D)[d4] = v;
    }
}

// ================= atomic fallback path =================

__global__ void k_count(const int* __restrict__ col, int* __restrict__ deg, int E) {
    int e = blockIdx.x * blockDim.x + threadIdx.x;
    if (e < E) atomicAdd(&deg[col[e]], 1);
}

template <int KD, int OD, bool SCALE>
__global__ void k_mm(const float* __restrict__ xin, const float* __restrict__ W,
                     const float* __restrict__ dinv, float* __restrict__ hout, int N) {
    __shared__ float Ws[KD * OD];
    for (int t = threadIdx.x; t < KD * OD; t += blockDim.x) Ws[t] = W[t];
    __syncthreads();
    int idx = blockIdx.x * blockDim.x + threadIdx.x;
    int i = idx / OD, d = idx % OD;
    if (i >= N) return;
    const float4* xr = reinterpret_cast<const float4*>(xin + (long)i * KD);
    float acc = 0.f;
#pragma unroll
    for (int k4 = 0; k4 < KD / 4; ++k4) {
        float4 xv = xr[k4];
        acc = fmaf(xv.x, Ws[(4 * k4 + 0) * OD + d], acc);
        acc = fmaf(xv.y, Ws[(4 * k4 + 1) * OD + d], acc);
        acc = fmaf(xv.z, Ws[(4 * k4 + 2) * OD + d], acc);
        acc = fmaf(xv.w, Ws[(4 * k4 + 3) * OD + d], acc);
    }
    hout[idx] = SCALE ? acc * dinv[i] : acc;
}

__global__ void k_dinv_i(const int* __restrict__ deg, float* __restrict__ dinv, int N) {
    int i = blockIdx.x * blockDim.x + threadIdx.x;
    if (i < N) dinv[i] = rsqrtf((float)deg[i] + 1.0f);
}

template <int D>
__global__ void k_scatter(const int* __restrict__ row, const int* __restrict__ col,
                          const float* __restrict__ dinv, const float* __restrict__ hin,
                          float* __restrict__ agg, int E) {
    int idx = blockIdx.x * blockDim.x + threadIdx.x;
    int e = idx / D, d = idx % D;
    if (e >= E) return;
    int r = row[e], c = col[e];
    float nrm = dinv[r] * dinv[c];
    atomicAdd(&agg[(long)c * D + d], hin[(long)r * D + d] * nrm);
}

template <int D, bool RELU>
__global__ void k_finish(const float* __restrict__ hproj, const float* __restrict__ dinv,
                         const float* __restrict__ bias, float* __restrict__ agg, int N) {
    int idx = blockIdx.x * blockDim.x + threadIdx.x;
    if (idx >= N * D) return;
    int i = idx / D, d = idx % D;
    float di = dinv[i];
    float v = agg[idx] + hproj[idx] * di * di + bias[d];
    agg[idx] = RELU ? fmaxf(v, 0.f) : v;
}

// ================= decode (R16 config, best measured): out[i][j]=dot(z_i,z_j)
// 64x256 tile, 512 threads, 8x4 register tile, ty=t>>6 (8 waves = 8 row
// groups), tx=t&63. Each store instruction = 64 lanes x float4 = 1KB contiguous
// in ONE row. a-reads wave-uniform broadcasts; b-reads 1KB stride-1.
#define DTI 64
#define DTJ 256

__global__ __launch_bounds__(512, 8)
void k_decode(const float* __restrict__ z, float* __restrict__ out, int N) {
    __shared__ float ziT[16][DTI];    // 4 KB
    __shared__ float zjT[16][DTJ];    // 16 KB
    int bi = blockIdx.y * DTI, bj = blockIdx.x * DTJ;
    int t = threadIdx.x;

    {
        // zj: 256 rows x 64B; thread t -> row t>>1, 32B half (t&1)
        int r = t >> 1;
        int half = t & 1;
        int k0 = half * 8;
        {
            int gj = bj + r;
            float4 v0 = make_float4(0.f, 0.f, 0.f, 0.f), v1 = v0;
            if (gj < N) {
                const float4* zp = reinterpret_cast<const float4*>(z + (long)gj * 16);
                v0 = zp[half * 2];
                v1 = zp[half * 2 + 1];
            }
            float vals[8] = {v0.x, v0.y, v0.z, v0.w, v1.x, v1.y, v1.z, v1.w};
#pragma unroll
            for (int k = 0; k < 8; ++k) zjT[k0 + k][r] = vals[k];
        }
        // zi: 64 rows x 64B; threads 0..127
        if (t < 128) {
            int ri = t >> 1;
            int gi = bi + ri;
            float4 w0 = make_float4(0.f, 0.f, 0.f, 0.f), w1 = w0;
            if (gi < N) {
                const float4* zp = reinterpret_cast<const float4*>(z + (long)gi * 16);
                w0 = zp[half * 2];
                w1 = zp[half * 2 + 1];
            }
            float wv[8] = {w0.x, w0.y, w0.z, w0.w, w1.x, w1.y, w1.z, w1.w};
#pragma unroll
            for (int k = 0; k < 8; ++k) ziT[k0 + k][ri] = wv[k];
        }
    }
    __syncthreads();

    int tx = t & 63, ty = t >> 6;   // ty 0..7: rows ty*8..ty*8+7; tx 0..63: cols tx*4..+3
    float acc[8][4] = {};
#pragma unroll 4
    for (int k = 0; k < 16; ++k) {
        float a[8], b[4];
        float4 a0 = *reinterpret_cast<const float4*>(&ziT[k][ty * 8]);       // wave-uniform
        float4 a1 = *reinterpret_cast<const float4*>(&ziT[k][ty * 8 + 4]);   // wave-uniform
        float4 b0 = *reinterpret_cast<const float4*>(&zjT[k][tx * 4]);       // 1KB stride-1
        a[0]=a0.x; a[1]=a0.y; a[2]=a0.z; a[3]=a0.w; a[4]=a1.x; a[5]=a1.y; a[6]=a1.z; a[7]=a1.w;
        b[0]=b0.x; b[1]=b0.y; b[2]=b0.z; b[3]=b0.w;
#pragma unroll
        for (int u = 0; u < 8; ++u)
#pragma unroll
            for (int v = 0; v < 4; ++v)
                acc[u][v] = fmaf(a[u], b[v], acc[u][v]);
    }

#pragma unroll
    for (int u = 0; u < 8; ++u) {
        int gi = bi + ty * 8 + u;
        if (gi >= N) continue;
        int gj = bj + tx * 4;
        long base = (long)gi * N + gj;
        if (gj + 3 < N) {
            *reinterpret_cast<float4*>(&out[base]) =
                make_float4(acc[u][0], acc[u][1], acc[u][2], acc[u][3]);
        } else {
            for (int v2 = 0; v2 < 4; ++v2)
                if (gj + v2 < N) out[base + v2] = acc[u][v2];
        }
    }
}

// ================= launch =================

extern "C" void kernel_launch(void* const* d_in, const int* in_sizes, int n_in,
                              void* d_out, int out_size, void* d_ws, size_t ws_size,
                              hipStream_t stream) {
    const float* x  = (const float*)d_in[0];
    const int*   ei = (const int*)d_in[1];
    const float* W1 = (const float*)d_in[2];
    const float* b1 = (const float*)d_in[3];
    const float* W2 = (const float*)d_in[4];
    const float* b2 = (const float*)d_in[5];
    float* out = (float*)d_out;

    const int N = in_sizes[0] / IN_DIM;   // 10000
    const int E = in_sizes[1] / 2;        // 640000
    const int* row = ei;
    const int* col = ei + E;

    const long SZ_DEG = (N + 15) & ~15L;        // 10000
    const long SZ_BIN = (long)N * PAD;          // 1.6M ints (PAD=160)
    const long SZ_DI  = SZ_DEG;
    const long need = SZ_DEG + SZ_BIN + SZ_DI
                    + (long)N * H1 + 2L * N * H2;

    dim3 dgrid((N + DTJ - 1) / DTJ, (N + DTI - 1) / DTI);   // (40, 157)

    if (ws_size >= (size_t)need * 4) {
        // ---- padded-bin path (6 dispatches incl. decode) ----
        int*   deg    = (int*)d_ws;
        int*   csrpad = deg + SZ_DEG;
        float* dinv   = (float*)(csrpad + SZ_BIN);
        float* h      = dinv + SZ_DI;        // x@W1 (raw, then *dinv in k_prep)
        float* h2p    = h + (long)N * H1;    // (h1@W2)*dinv  (N*H2)
        float* zz     = h2p + (long)N * H2;  // z             (N*H2), 64B-aligned

        hipMemsetAsync(deg, 0, (size_t)N * sizeof(int), stream);

        int fillBlocks = (E + 255) / 256;                    // 2500
        int mmBlocks   = (N + XNODES - 1) / XNODES;          // 1250
        k_fill_mm1<<<fillBlocks + mmBlocks, 256, 0, stream>>>(
            row, col, deg, csrpad, E, x, W1, h, N, fillBlocks);

        k_prep<<<(N + 255) / 256, 256, 0, stream>>>(deg, dinv, h, N);

        k_g1mm2<<<(N + 3) / 4, 256, 0, stream>>>(deg, csrpad, dinv, h, b1, W2, h2p, N);
        k_gather<H2, false><<<(N + 3) / 4, 256, 0, stream>>>(deg, csrpad, dinv, h2p, b2, zz, N);

        k_decode<<<dgrid, 512, 0, stream>>>(zz, out, N);
    } else {
        // ---- fallback: atomic scatter path ----
        int*   deg  = (int*)d_ws;
        float* dinv = (float*)(deg + SZ_DEG);
        float* h    = dinv + SZ_DI;
        float* h1   = h + (long)N * H1;
        float* h2   = h1 + (long)N * H1;
        float* zz   = h2 + (long)N * H2;

        hipMemsetAsync(deg, 0, (size_t)N * sizeof(int), stream);
        hipMemsetAsync(h1, 0, (size_t)N * H1 * sizeof(float), stream);
        hipMemsetAsync(zz, 0, (size_t)N * H2 * sizeof(float), stream);

        k_count<<<(E + 255) / 256, 256, 0, stream>>>(col, deg, E);
        k_dinv_i<<<(N + 255) / 256, 256, 0, stream>>>(deg, dinv, N);

        k_mm<IN_DIM, H1, false><<<((long)N * H1 + 255) / 256, 256, 0, stream>>>(x, W1, dinv, h, N);
        k_scatter<H1><<<((long)E * H1 + 255) / 256, 256, 0, stream>>>(row, col, dinv, h, h1, E);
        k_finish<H1, true><<<((long)N * H1 + 255) / 256, 256, 0, stream>>>(h, dinv, b1, h1, N);

        k_mm<H1, H2, false><<<((long)N * H2 + 255) / 256, 256, 0, stream>>>(h1, W2, dinv, h2, N);
        k_scatter<H2><<<((long)E * H2 + 255) / 256, 256, 0, stream>>>(row, col, dinv, h2, zz, E);
        k_finish<H2, false><<<((long)N * H2 + 255) / 256, 256, 0, stream>>>(h2, dinv, b2, zz, N);

        k_decode<<<dgrid, 512, 0, stream>>>(zz, out, N);
    }
}

// Round 19
// 163.319 us; speedup vs baseline: 1.1273x; 1.0238x over previous
//
#include <hip/hip_runtime.h>

#define IN_DIM 128
#define H1 32
#define H2 16
#define PAD 160   // padded bin capacity: Poisson(64) edges/node, 160 = +12 sigma
#define XNODES 8

// ================= fused: bin-fill w/ count (blocks 0..FB-1) || mm1 (FB..) ===
__global__ void k_fill_mm1(const int* __restrict__ row, const int* __restrict__ col,
                           int* __restrict__ deg, int* __restrict__ csrpad, int E,
                           const float* __restrict__ x, const float* __restrict__ W1,
                           float* __restrict__ hout, int N, int fillBlocks) {
    __shared__ float Ws[IN_DIM * H1];          // 16 KB
    __shared__ float xs[XNODES][IN_DIM];       // 4 KB
    if ((int)blockIdx.x < fillBlocks) {
        int e = blockIdx.x * blockDim.x + threadIdx.x;
        if (e < E) {
            int c = col[e];
            int pos = atomicAdd(&deg[c], 1);
            csrpad[(long)c * PAD + pos] = row[e];
        }
        return;   // whole block exits; no barrier crossed
    }
    int t = threadIdx.x;
    int i0 = ((int)blockIdx.x - fillBlocks) * XNODES;
    const float4* W4 = reinterpret_cast<const float4*>(W1);
    float4* Ws4 = reinterpret_cast<float4*>(Ws);
#pragma unroll
    for (int i = t; i < IN_DIM * H1 / 4; i += 256) Ws4[i] = W4[i];
    const float4* xg = reinterpret_cast<const float4*>(x + (long)i0 * IN_DIM);
    float4* xs4 = reinterpret_cast<float4*>(xs);
    xs4[t] = xg[t];   // XNODES*IN_DIM/4 == 256 exactly
    __syncthreads();
    int n = t >> 5, d = t & 31;
    float acc = 0.f;
#pragma unroll 8
    for (int k = 0; k < IN_DIM; ++k) acc = fmaf(xs[n][k], Ws[k * H1 + d], acc);
    int i = i0 + n;
    if (i < N) hout[(long)i * H1 + d] = acc;
}

// ================= prep: dinv = rsqrt(deg+1); h *= dinv (in place) ===========
__global__ void k_prep(const int* __restrict__ deg, float* __restrict__ dinv,
                       float* __restrict__ h, int N) {
    int i = blockIdx.x * blockDim.x + threadIdx.x;
    if (i >= N) return;
    float di = rsqrtf((float)deg[i] + 1.0f);
    dinv[i] = di;
    float4* hp = reinterpret_cast<float4*>(h + (long)i * H1);
#pragma unroll
    for (int q = 0; q < H1 / 4; ++q) {
        float4 v = hp[q];
        v.x *= di; v.y *= di; v.z *= di; v.w *= di;
        hp[q] = v;
    }
}

// ================= fused gather1 + mm2 (padded bins, 8-deep MLP) =============
__global__ void k_g1mm2(const int* __restrict__ deg, const int* __restrict__ csrpad,
                        const float* __restrict__ dinv, const float* __restrict__ hp,
                        const float* __restrict__ b1, const float* __restrict__ W2,
                        float* __restrict__ h2p, int N) {
    __shared__ float W2s[H1 * H2];     // 2 KB
    __shared__ float h1s[4][H1];       // per-wave slot
    int t = threadIdx.x;
    for (int i = t; i < H1 * H2; i += blockDim.x) W2s[i] = W2[i];
    __syncthreads();
    int wv = t >> 6;
    int lane = t & 63;
    int c = blockIdx.x * 4 + wv;
    bool active = (c < N);
    int cc = active ? c : (N - 1);     // clamp: inactive waves do harmless reads
    constexpr int C4 = H1 / 4;         // 8 float4 chunks
    constexpr int SUB = 64 / C4;       // 8 edges per wave-iter
    int sub = lane / C4, d4 = lane % C4;
    int cnt = deg[cc];
    const int* bin = csrpad + (long)cc * PAD;
    const float4* hp4 = reinterpret_cast<const float4*>(hp);

    float4 A0 = make_float4(0.f, 0.f, 0.f, 0.f), A1 = A0, A2 = A0, A3 = A0;
    int k = sub;
    for (; k + 7 * SUB < cnt; k += 8 * SUB) {   // 8 loads in flight (cnt~64 -> one batch)
        int s0 = bin[k];
        int s1 = bin[k + SUB];
        int s2 = bin[k + 2 * SUB];
        int s3 = bin[k + 3 * SUB];
        int s4 = bin[k + 4 * SUB];
        int s5 = bin[k + 5 * SUB];
        int s6 = bin[k + 6 * SUB];
        int s7 = bin[k + 7 * SUB];
        float4 v0 = hp4[(long)s0 * C4 + d4];
        float4 v1 = hp4[(long)s1 * C4 + d4];
        float4 v2 = hp4[(long)s2 * C4 + d4];
        float4 v3 = hp4[(long)s3 * C4 + d4];
        float4 v4 = hp4[(long)s4 * C4 + d4];
        float4 v5 = hp4[(long)s5 * C4 + d4];
        float4 v6 = hp4[(long)s6 * C4 + d4];
        float4 v7 = hp4[(long)s7 * C4 + d4];
        A0.x += v0.x; A0.y += v0.y; A0.z += v0.z; A0.w += v0.w;
        A1.x += v1.x; A1.y += v1.y; A1.z += v1.z; A1.w += v1.w;
        A2.x += v2.x; A2.y += v2.y; A2.z += v2.z; A2.w += v2.w;
        A3.x += v3.x; A3.y += v3.y; A3.z += v3.z; A3.w += v3.w;
        A0.x += v4.x; A0.y += v4.y; A0.z += v4.z; A0.w += v4.w;
        A1.x += v5.x; A1.y += v5.y; A1.z += v5.z; A1.w += v5.w;
        A2.x += v6.x; A2.y += v6.y; A2.z += v6.z; A2.w += v6.w;
        A3.x += v7.x; A3.y += v7.y; A3.z += v7.z; A3.w += v7.w;
    }
    for (; k + 3 * SUB < cnt; k += 4 * SUB) {
        int s0 = bin[k];
        int s1 = bin[k + SUB];
        int s2 = bin[k + 2 * SUB];
        int s3 = bin[k + 3 * SUB];
        float4 v0 = hp4[(long)s0 * C4 + d4];
        float4 v1 = hp4[(long)s1 * C4 + d4];
        float4 v2 = hp4[(long)s2 * C4 + d4];
        float4 v3 = hp4[(long)s3 * C4 + d4];
        A0.x += v0.x; A0.y += v0.y; A0.z += v0.z; A0.w += v0.w;
        A1.x += v1.x; A1.y += v1.y; A1.z += v1.z; A1.w += v1.w;
        A2.x += v2.x; A2.y += v2.y; A2.z += v2.z; A2.w += v2.w;
        A3.x += v3.x; A3.y += v3.y; A3.z += v3.z; A3.w += v3.w;
    }
    for (; k < cnt; k += SUB) {
        float4 v = hp4[(long)bin[k] * C4 + d4];
        A0.x += v.x; A0.y += v.y; A0.z += v.z; A0.w += v.w;
    }
    float4 acc;
    acc.x = (A0.x + A1.x) + (A2.x + A3.x);
    acc.y = (A0.y + A1.y) + (A2.y + A3.y);
    acc.z = (A0.z + A1.z) + (A2.z + A3.z);
    acc.w = (A0.w + A1.w) + (A2.w + A3.w);
#pragma unroll
    for (int off = C4; off < 64; off <<= 1) {
        acc.x += __shfl_xor(acc.x, off, 64);
        acc.y += __shfl_xor(acc.y, off, 64);
        acc.z += __shfl_xor(acc.z, off, 64);
        acc.w += __shfl_xor(acc.w, off, 64);
    }
    if (lane < C4) {
        float di = dinv[cc];
        float4 self = hp4[(long)cc * C4 + d4];
        float4 bv = reinterpret_cast<const float4*>(b1)[d4];
        float4 v;
        v.x = fmaxf(fmaf(di, acc.x + self.x, bv.x), 0.f);
        v.y = fmaxf(fmaf(di, acc.y + self.y, bv.y), 0.f);
        v.z = fmaxf(fmaf(di, acc.z + self.z, bv.z), 0.f);
        v.w = fmaxf(fmaf(di, acc.w + self.w, bv.w), 0.f);
        reinterpret_cast<float4*>(h1s[wv])[d4] = v;
    }
    __syncthreads();   // all threads reach (no early returns)
    if (active && lane < H2) {
        float z = 0.f;
#pragma unroll
        for (int kk = 0; kk < H1; ++kk) z = fmaf(h1s[wv][kk], W2s[kk * H2 + lane], z);
        h2p[(long)c * H2 + lane] = z * dinv[c];
    }
}

// ================= gather layer 2 (padded bins), float4 lanes ================
template <int D, bool RELU>
__global__ void k_gather(const int* __restrict__ deg, const int* __restrict__ csrpad,
                         const float* __restrict__ dinv, const float* __restrict__ hp,
                         const float* __restrict__ bias, float* __restrict__ out, int N) {
    constexpr int C4  = D / 4;
    constexpr int SUB = 64 / C4;
    int c = blockIdx.x * (blockDim.x >> 6) + (threadIdx.x >> 6);
    if (c >= N) return;
    int lane = threadIdx.x & 63;
    int sub = lane / C4, d4 = lane % C4;
    int cnt = deg[c];
    const int* bin = csrpad + (long)c * PAD;
    const float4* hp4 = reinterpret_cast<const float4*>(hp);

    float4 A0 = make_float4(0.f, 0.f, 0.f, 0.f), A1 = A0, A2 = A0, A3 = A0;
    int k = sub;
    for (; k + 3 * SUB < cnt; k += 4 * SUB) {
        int s0 = bin[k];
        int s1 = bin[k + SUB];
        int s2 = bin[k + 2 * SUB];
        int s3 = bin[k + 3 * SUB];
        float4 v0 = hp4[(long)s0 * C4 + d4];
        float4 v1 = hp4[(long)s1 * C4 + d4];
        float4 v2 = hp4[(long)s2 * C4 + d4];
        float4 v3 = hp4[(long)s3 * C4 + d4];
        A0.x += v0.x; A0.y += v0.y; A0.z += v0.z; A0.w += v0.w;
        A1.x += v1.x; A1.y += v1.y; A1.z += v1.z; A1.w += v1.w;
        A2.x += v2.x; A2.y += v2.y; A2.z += v2.z; A2.w += v2.w;
        A3.x += v3.x; A3.y += v3.y; A3.z += v3.z; A3.w += v3.w;
    }
    for (; k < cnt; k += SUB) {
        float4 v = hp4[(long)bin[k] * C4 + d4];
        A0.x += v.x; A0.y += v.y; A0.z += v.z; A0.w += v.w;
    }
    float4 acc;
    acc.x = (A0.x + A1.x) + (A2.x + A3.x);
    acc.y = (A0.y + A1.y) + (A2.y + A3.y);
    acc.z = (A0.z + A1.z) + (A2.z + A3.z);
    acc.w = (A0.w + A1.w) + (A2.w + A3.w);
#pragma unroll
    for (int off = C4; off < 64; off <<= 1) {
        acc.x += __shfl_xor(acc.x, off, 64);
        acc.y += __shfl_xor(acc.y, off, 64);
        acc.z += __shfl_xor(acc.z, off, 64);
        acc.w += __shfl_xor(acc.w, off, 64);
    }
    if (lane < C4) {
        float di = dinv[c];
        float4 self = hp4[(long)c * C4 + d4];
        float4 bv = reinterpret_cast<const float4*>(bias)[d4];
        float4 v;
        v.x = fmaf(di, acc.x + self.x, bv.x);
        v.y = fmaf(di, acc.y + self.y, bv.y);
        v.z = fmaf(di, acc.z + self.z, bv.z);
        v.w = fmaf(di, acc.w + self.w, bv.w);
        if (RELU) {
            v.x = fmaxf(v.x, 0.f); v.y = fmaxf(v.y, 0.f);
            v.z = fmaxf(v.z, 0.f); v.w = fmaxf(v.w, 0.f);
        }
        reinterpret_cast<float4*>(out + (long)c * D)[d4] = v;
    }
}

// ================= atomic fallback path =================

__global__ void k_count(const int* __restrict__ col, int* __restrict__ deg, int E) {
    int e = blockIdx.x * blockDim.x + threadIdx.x;
    if (e < E) atomicAdd(&deg[col[e]], 1);
}

template <int KD, int OD, bool SCALE>
__global__ void k_mm(const float* __restrict__ xin, const float* __restrict__ W,
                     const float* __restrict__ dinv, float* __restrict__ hout, int N) {
    __shared__ float Ws[KD * OD];
    for (int t = threadIdx.x; t < KD * OD; t += blockDim.x) Ws[t] = W[t];
    __syncthreads();
    int idx = blockIdx.x * blockDim.x + threadIdx.x;
    int i = idx / OD, d = idx % OD;
    if (i >= N) return;
    const float4* xr = reinterpret_cast<const float4*>(xin + (long)i * KD);
    float acc = 0.f;
#pragma unroll
    for (int k4 = 0; k4 < KD / 4; ++k4) {
        float4 xv = xr[k4];
        acc = fmaf(xv.x, Ws[(4 * k4 + 0) * OD + d], acc);
        acc = fmaf(xv.y, Ws[(4 * k4 + 1) * OD + d], acc);
        acc = fmaf(xv.z, Ws[(4 * k4 + 2) * OD + d], acc);
        acc = fmaf(xv.w, Ws[(4 * k4 + 3) * OD + d], acc);
    }
    hout[idx] = SCALE ? acc * dinv[i] : acc;
}

__global__ void k_dinv_i(const int* __restrict__ deg, float* __restrict__ dinv, int N) {
    int i = blockIdx.x * blockDim.x + threadIdx.x;
    if (i < N) dinv[i] = rsqrtf((float)deg[i] + 1.0f);
}

template <int D>
__global__ void k_scatter(const int* __restrict__ row, const int* __restrict__ col,
                          const float* __restrict__ dinv, const float* __restrict__ hin,
                          float* __restrict__ agg, int E) {
    int idx = blockIdx.x * blockDim.x + threadIdx.x;
    int e = idx / D, d = idx % D;
    if (e >= E) return;
    int r = row[e], c = col[e];
    float nrm = dinv[r] * dinv[c];
    atomicAdd(&agg[(long)c * D + d], hin[(long)r * D + d] * nrm);
}

template <int D, bool RELU>
__global__ void k_finish(const float* __restrict__ hproj, const float* __restrict__ dinv,
                         const float* __restrict__ bias, float* __restrict__ agg, int N) {
    int idx = blockIdx.x * blockDim.x + threadIdx.x;
    if (idx >= N * D) return;
    int i = idx / D, d = idx % D;
    float di = dinv[i];
    float v = agg[idx] + hproj[idx] * di * di + bias[d];
    agg[idx] = RELU ? fmaxf(v, 0.f) : v;
}

// ================= decode: out[i][j] = dot(z[i], z[j]) =======================
// R19: 64x512 tile, 512 threads, 8x8 register tile. Per k-step: 2 wave-uniform
// a-reads + 2 b-reads per 64 FMA — LDS instr/FMA HALVED vs R16 (the per-CU LDS
// pipe is the one shape-dependent cost left). Stores keep the 1KB-contiguous
// per-instruction pattern (cols tx*4 and 256+tx*4). k-order per output
// unchanged -> bit-identical. LDS 36KB -> >=2 blocks/CU.
#define DTI 64
#define DTJ 512

__global__ __launch_bounds__(512, 4)
void k_decode(const float* __restrict__ z, float* __restrict__ out, int N) {
    __shared__ float ziT[16][DTI];    // 4 KB
    __shared__ float zjT[16][DTJ];    // 32 KB
    int bi = blockIdx.y * DTI, bj = blockIdx.x * DTJ;
    int t = threadIdx.x;

    {
        // zj: 512 rows x 64B; thread t -> full row t (4x float4)
        int gj = bj + t;
        float4 v0 = make_float4(0.f, 0.f, 0.f, 0.f), v1 = v0, v2 = v0, v3 = v0;
        if (gj < N) {
            const float4* zp = reinterpret_cast<const float4*>(z + (long)gj * 16);
            v0 = zp[0]; v1 = zp[1]; v2 = zp[2]; v3 = zp[3];
        }
        float vals[16] = {v0.x, v0.y, v0.z, v0.w, v1.x, v1.y, v1.z, v1.w,
                          v2.x, v2.y, v2.z, v2.w, v3.x, v3.y, v3.z, v3.w};
#pragma unroll
        for (int k = 0; k < 16; ++k) zjT[k][t] = vals[k];   // lanes stride-1: no conflict
        // zi: 64 rows; threads 0..63 load full rows
        if (t < 64) {
            int gi = bi + t;
            float4 w0 = make_float4(0.f, 0.f, 0.f, 0.f), w1 = w0, w2 = w0, w3 = w0;
            if (gi < N) {
                const float4* zp = reinterpret_cast<const float4*>(z + (long)gi * 16);
                w0 = zp[0]; w1 = zp[1]; w2 = zp[2]; w3 = zp[3];
            }
            float wv[16] = {w0.x, w0.y, w0.z, w0.w, w1.x, w1.y, w1.z, w1.w,
                            w2.x, w2.y, w2.z, w2.w, w3.x, w3.y, w3.z, w3.w};
#pragma unroll
            for (int k = 0; k < 16; ++k) ziT[k][t] = wv[k];
        }
    }
    __syncthreads();

    int tx = t & 63, ty = t >> 6;   // ty 0..7: rows ty*8..+7; tx 0..63: col groups
    float acc[8][8] = {};
#pragma unroll 4
    for (int k = 0; k < 16; ++k) {
        float a[8], b[8];
        float4 a0 = *reinterpret_cast<const float4*>(&ziT[k][ty * 8]);        // wave-uniform
        float4 a1 = *reinterpret_cast<const float4*>(&ziT[k][ty * 8 + 4]);    // wave-uniform
        float4 b0 = *reinterpret_cast<const float4*>(&zjT[k][tx * 4]);        // 1KB stride-1
        float4 b1 = *reinterpret_cast<const float4*>(&zjT[k][256 + tx * 4]);  // 1KB stride-1
        a[0]=a0.x; a[1]=a0.y; a[2]=a0.z; a[3]=a0.w; a[4]=a1.x; a[5]=a1.y; a[6]=a1.z; a[7]=a1.w;
        b[0]=b0.x; b[1]=b0.y; b[2]=b0.z; b[3]=b0.w; b[4]=b1.x; b[5]=b1.y; b[6]=b1.z; b[7]=b1.w;
#pragma unroll
        for (int u = 0; u < 8; ++u)
#pragma unroll
            for (int v = 0; v < 8; ++v)
                acc[u][v] = fmaf(a[u], b[v], acc[u][v]);
    }

#pragma unroll
    for (int u = 0; u < 8; ++u) {
        int gi = bi + ty * 8 + u;
        if (gi >= N) continue;
        long rowb = (long)gi * N;
        int gj0 = bj + tx * 4;
        int gj1 = bj + 256 + tx * 4;
        if (gj0 + 3 < N) {
            *reinterpret_cast<float4*>(&out[rowb + gj0]) =
                make_float4(acc[u][0], acc[u][1], acc[u][2], acc[u][3]);
        } else {
            for (int v2 = 0; v2 < 4; ++v2)
                if (gj0 + v2 < N) out[rowb + gj0 + v2] = acc[u][v2];
        }
        if (gj1 + 3 < N) {
            *reinterpret_cast<float4*>(&out[rowb + gj1]) =
                make_float4(acc[u][4], acc[u][5], acc[u][6], acc[u][7]);
        } else {
            for (int v2 = 0; v2 < 4; ++v2)
                if (gj1 + v2 < N) out[rowb + gj1 + v2] = acc[u][4 + v2];
        }
    }
}

// ================= launch =================

extern "C" void kernel_launch(void* const* d_in, const int* in_sizes, int n_in,
                              void* d_out, int out_size, void* d_ws, size_t ws_size,
                              hipStream_t stream) {
    const float* x  = (const float*)d_in[0];
    const int*   ei = (const int*)d_in[1];
    const float* W1 = (const float*)d_in[2];
    const float* b1 = (const float*)d_in[3];
    const float* W2 = (const float*)d_in[4];
    const float* b2 = (const float*)d_in[5];
    float* out = (float*)d_out;

    const int N = in_sizes[0] / IN_DIM;   // 10000
    const int E = in_sizes[1] / 2;        // 640000
    const int* row = ei;
    const int* col = ei + E;

    const long SZ_DEG = (N + 15) & ~15L;        // 10000
    const long SZ_BIN = (long)N * PAD;          // 1.6M ints (PAD=160)
    const long SZ_DI  = SZ_DEG;
    const long need = SZ_DEG + SZ_BIN + SZ_DI
                    + (long)N * H1 + 2L * N * H2;

    dim3 dgrid((N + DTJ - 1) / DTJ, (N + DTI - 1) / DTI);   // (20, 157)

    if (ws_size >= (size_t)need * 4) {
        // ---- padded-bin path (6 dispatches incl. decode) ----
        int*   deg    = (int*)d_ws;
        int*   csrpad = deg + SZ_DEG;
        float* dinv   = (float*)(csrpad + SZ_BIN);
        float* h      = dinv + SZ_DI;        // x@W1 (raw, then *dinv in k_prep)
        float* h2p    = h + (long)N * H1;    // (h1@W2)*dinv  (N*H2)
        float* zz     = h2p + (long)N * H2;  // z             (N*H2), 64B-aligned

        hipMemsetAsync(deg, 0, (size_t)N * sizeof(int), stream);

        int fillBlocks = (E + 255) / 256;                    // 2500
        int mmBlocks   = (N + XNODES - 1) / XNODES;          // 1250
        k_fill_mm1<<<fillBlocks + mmBlocks, 256, 0, stream>>>(
            row, col, deg, csrpad, E, x, W1, h, N, fillBlocks);

        k_prep<<<(N + 255) / 256, 256, 0, stream>>>(deg, dinv, h, N);

        k_g1mm2<<<(N + 3) / 4, 256, 0, stream>>>(deg, csrpad, dinv, h, b1, W2, h2p, N);
        k_gather<H2, false><<<(N + 3) / 4, 256, 0, stream>>>(deg, csrpad, dinv, h2p, b2, zz, N);

        k_decode<<<dgrid, 512, 0, stream>>>(zz, out, N);
    } else {
        // ---- fallback: atomic scatter path ----
        int*   deg  = (int*)d_ws;
        float* dinv = (float*)(deg + SZ_DEG);
        float* h    = dinv + SZ_DI;
        float* h1   = h + (long)N * H1;
        float* h2   = h1 + (long)N * H1;
        float* zz   = h2 + (long)N * H2;

        hipMemsetAsync(deg, 0, (size_t)N * sizeof(int), stream);
        hipMemsetAsync(h1, 0, (size_t)N * H1 * sizeof(float), stream);
        hipMemsetAsync(zz, 0, (size_t)N * H2 * sizeof(float), stream);

        k_count<<<(E + 255) / 256, 256, 0, stream>>>(col, deg, E);
        k_dinv_i<<<(N + 255) / 256, 256, 0, stream>>>(deg, dinv, N);

        k_mm<IN_DIM, H1, false><<<((long)N * H1 + 255) / 256, 256, 0, stream>>>(x, W1, dinv, h, N);
        k_scatter<H1><<<((long)E * H1 + 255) / 256, 256, 0, stream>>>(row, col, dinv, h, h1, E);
        k_finish<H1, true><<<((long)N * H1 + 255) / 256, 256, 0, stream>>>(h, dinv, b1, h1, N);

        k_mm<H1, H2, false><<<((long)N * H2 + 255) / 256, 256, 0, stream>>>(h1, W2, dinv, h2, N);
        k_scatter<H2><<<((long)E * H2 + 255) / 256, 256, 0, stream>>>(row, col, dinv, h2, zz, E);
        k_finish<H2, false><<<((long)N * H2 + 255) / 256, 256, 0, stream>>>(h2, dinv, b2, zz, N);

        k_decode<<<dgrid, 512, 0, stream>>>(zz, out, N);
    }
}